// Round 8
// baseline (1598.306 us; speedup 1.0000x reference)
//
#include <hip/hip_runtime.h>
#include <hip/hip_fp16.h>

static constexpr int BLK   = 256;   // generic block size
static constexpr int B1    = 256;   // partition blocks for hist/scatter
static constexpr int BLKW  = 1024;  // threads for hist/scatter/iter blocks
static constexpr int RSH   = 14;    // rows per bucket = 16384
static constexpr int RPB   = 16384;
static constexpr int RMSK  = 16383;
static constexpr int NCH   = 128;   // col-high bins (col>>13) per rowbucket
static constexpr int CHSH  = 13;
static constexpr int NCS   = 8;     // iter col splits (col>>17), == #XCDs
static constexpr int NSMAX = 8192;  // >= 7936 segments
static constexpr int FCAP  = 3072;  // finesort stage capacity (mean 2016, 23 sigma)

typedef unsigned long long ull;
typedef unsigned int uint;

// --- detect whether edgeij_pair is int64 (expected) or int32 (JAX x64 off) ---
__global__ void detect_kernel(const ull* __restrict__ rc, int* __restrict__ flag) {
    if (blockIdx.x == 0 && threadIdx.x == 0) {
        int is64 = 1;
        for (int i = 0; i < 8; ++i)
            if (rc[i] >= (1ull << 20)) is64 = 0;
        *flag = is64;
    }
}

// --- hist of seg = (row>>RSH)*NCH + (col>>CHSH) -> hist[seg*B1 + blk] ---
__global__ void hist1_kernel(const void* __restrict__ rcv,
                             const int* __restrict__ flag,
                             uint* __restrict__ hist, int ne, int nseg) {
    __shared__ uint lh[NSMAX];
    const int b = blockIdx.x;
    const int chunk = (ne + B1 - 1) / B1;
    const int s = b * chunk, e = min(ne, s + chunk);
    for (int i = threadIdx.x; i < NSMAX; i += BLKW) lh[i] = 0u;
    __syncthreads();
    const int is64 = *flag;
    const ull*  r64 = (const ull*)rcv;
    const uint* r32 = (const uint*)rcv;
    for (int i = s + threadIdx.x; i < e; i += BLKW) {
        uint row, col;
        if (is64) { row = (uint)r64[i]; col = (uint)r64[(size_t)ne + i]; }
        else      { row = r32[i];       col = r32[(size_t)ne + i]; }
        atomicAdd(&lh[(row >> RSH) * NCH + (col >> CHSH)], 1u);
    }
    __syncthreads();
    for (int i = threadIdx.x; i < nseg; i += BLKW)
        hist[(size_t)i * B1 + b] = lh[i];
}

// --- generic scan: per-block exclusive scan (in-place), totals to part ---
__global__ void scan1_kernel(uint* __restrict__ data,
                             uint* __restrict__ part, int n) {
    __shared__ uint s[BLK];
    int t = threadIdx.x;
    int i = blockIdx.x * BLK + t;
    uint v = (i < n) ? data[i] : 0u;
    s[t] = v;
    __syncthreads();
    for (int off = 1; off < BLK; off <<= 1) {
        uint u = (t >= off) ? s[t - off] : 0u;
        __syncthreads();
        s[t] += u;
        __syncthreads();
    }
    if (i < n) data[i] = s[t] - v;
    if (t == BLK - 1) part[blockIdx.x] = s[t];
}

__global__ void scan2_kernel(uint* __restrict__ part, int np) {
    __shared__ uint s[BLK];
    __shared__ uint carry_s;
    int t = threadIdx.x;
    if (t == 0) carry_s = 0u;
    __syncthreads();
    for (int base = 0; base < np; base += BLK) {
        int i = base + t;
        uint v = (i < np) ? part[i] : 0u;
        s[t] = v;
        __syncthreads();
        for (int off = 1; off < BLK; off <<= 1) {
            uint u = (t >= off) ? s[t - off] : 0u;
            __syncthreads();
            s[t] += u;
            __syncthreads();
        }
        uint carry = carry_s;
        if (i < np) part[i] = s[t] - v + carry;
        __syncthreads();
        if (t == BLK - 1) carry_s = carry + s[t];
        __syncthreads();
    }
}

__global__ void scan3_kernel(uint* __restrict__ data,
                             const uint* __restrict__ part, int n) {
    int i = blockIdx.x * BLK + threadIdx.x;
    if (i < n) data[i] += part[blockIdx.x];
}

// --- scatter edges into fine segments; pack (row:20|col:20|a_f16) ---
__global__ void scatter1_kernel(const void* __restrict__ rcv,
                                const float2* __restrict__ eattr,
                                const int* __restrict__ flag,
                                const uint* __restrict__ base,
                                ull* __restrict__ edges, int ne, int nseg) {
    __shared__ uint cur[NSMAX];
    const int b = blockIdx.x;
    const int chunk = (ne + B1 - 1) / B1;
    const int s = b * chunk, e = min(ne, s + chunk);
    for (int i = threadIdx.x; i < nseg; i += BLKW)
        cur[i] = base[(size_t)i * B1 + b];
    __syncthreads();
    const int is64 = *flag;
    const ull*  r64 = (const ull*)rcv;
    const uint* r32 = (const uint*)rcv;
    for (int i = s + threadIdx.x; i < e; i += BLKW) {
        ull row, col;
        if (is64) { row = r64[i]; col = r64[(size_t)ne + i]; }
        else      { row = r32[i]; col = r32[(size_t)ne + i]; }
        float a = eattr[i].x;
        unsigned short h = __half_as_ushort(__float2half(a));
        ull q = (row << 44) | (col << 24) | (ull)h;
        uint seg = (uint)(row >> RSH) * NCH + (uint)(col >> CHSH);
        uint pos = atomicAdd(&cur[seg], 1u);
        edges[pos] = q;
    }
}

// --- per-segment counting sort by col-line (col>>4); emit SoA rc32 + a_f16 ---
// rc32 = (row & RMSK) << 17 | (col & 0x1FFFF)
__global__ void finesort_kernel(const ull* __restrict__ edges,
                                const uint* __restrict__ base,
                                uint* __restrict__ rc32,
                                unsigned short* __restrict__ af16,
                                int ne, int nseg) {
    __shared__ uint cnt[512];
    __shared__ uint cur[512];
    __shared__ uint ss[BLK];
    __shared__ uint  stage_rc[FCAP];
    __shared__ unsigned short stage_a[FCAP];
    const int seg = blockIdx.x;
    const int t = threadIdx.x;
    const uint s = base[(size_t)seg * B1];
    const uint e = (seg == nseg - 1) ? (uint)ne : base[(size_t)(seg + 1) * B1];
    const uint n = e - s;
    cnt[2 * t] = 0u; cnt[2 * t + 1] = 0u;
    __syncthreads();
    if (n <= (uint)FCAP) {
        for (uint j = s + t; j < e; j += BLK) {
            uint col = (uint)(edges[j] >> 24) & 0xFFFFFu;
            atomicAdd(&cnt[(col >> 4) & 511u], 1u);
        }
        __syncthreads();
        uint v0 = cnt[2 * t], v1 = cnt[2 * t + 1];
        uint tsum = v0 + v1;
        ss[t] = tsum;
        __syncthreads();
        for (int off = 1; off < BLK; off <<= 1) {
            uint u = (t >= off) ? ss[t - off] : 0u;
            __syncthreads();
            ss[t] += u;
            __syncthreads();
        }
        uint exc = ss[t] - tsum;
        cur[2 * t] = exc;
        cur[2 * t + 1] = exc + v0;
        __syncthreads();
        for (uint j = s + t; j < e; j += BLK) {
            ull q = edges[j];
            uint col = (uint)(q >> 24) & 0xFFFFFu;
            uint r   = (uint)(q >> 44) & RMSK;
            uint pos = atomicAdd(&cur[(col >> 4) & 511u], 1u);
            stage_rc[pos] = (r << 17) | (col & 0x1FFFFu);
            stage_a[pos]  = (unsigned short)(q & 0xFFFFu);
        }
        __syncthreads();
        for (uint k = t; k < n; k += BLK) {
            rc32[s + k] = stage_rc[k];
            af16[s + k] = stage_a[k];
        }
    } else {
        // overflow fallback: copy unsorted (correctness preserved)
        for (uint j = s + t; j < e; j += BLK) {
            ull q = edges[j];
            uint col = (uint)(q >> 24) & 0xFFFFFu;
            uint r   = (uint)(q >> 44) & RMSK;
            rc32[j] = (r << 17) | (col & 0x1FFFFu);
            af16[j] = (unsigned short)(q & 0xFFFFu);
        }
    }
}

// --- vertex preprocessing: wbA = w*b/A, wA = w/A, x0 ---
__global__ void vprep_kernel(const float* __restrict__ vattr,
                             const float* __restrict__ g,
                             float2* __restrict__ vp,
                             float* __restrict__ x0, int nv) {
    int i = blockIdx.x * BLK + threadIdx.x;
    if (i >= nv) return;
    float A = vattr[3 * i + 0];
    float b = vattr[3 * i + 1];
    float x = vattr[3 * i + 2];
    float w = g[0];
    vp[i] = make_float2(w * b / A, w / A);
    x0[i] = x;
}

// --- iteration phase A: block (rb, cs); col-sorted gathers coalesce ---
__global__ __launch_bounds__(BLKW)
void iter_kernel(const uint* __restrict__ segstart,   // hist after scan
                 const uint* __restrict__ rc32,
                 const unsigned short* __restrict__ af16,
                 const float* __restrict__ xin,
                 float* __restrict__ p,                // NCS planes of nprows
                 int ne, int nseg, int nprows) {
    __shared__ float acc[RPB];
    const int i = blockIdx.x;
    const int rb = i >> 3, cs = i & 7;
    const int t = threadIdx.x;
    #pragma unroll
    for (int k = t; k < RPB; k += BLKW) acc[k] = 0.0f;
    __syncthreads();
    const int seg0 = rb * NCH + cs * (NCH / NCS);
    const int seg1 = seg0 + (NCH / NCS);
    const uint s = segstart[(size_t)seg0 * B1];
    const uint e = (seg1 >= nseg) ? (uint)ne : segstart[(size_t)seg1 * B1];
    const uint cbase = (uint)cs << 17;
    #pragma unroll 4
    for (uint j = s + t; j < e; j += BLKW) {
        uint rc = rc32[j];
        float a = __half2float(__ushort_as_half(af16[j]));
        atomicAdd(&acc[rc >> 17], a * xin[cbase | (rc & 0x1FFFFu)]);
    }
    __syncthreads();
    float* plane = p + (size_t)cs * nprows + ((size_t)rb << RSH);
    #pragma unroll
    for (int k = t; k < RPB; k += BLKW) plane[k] = acc[k];
}

// --- iteration phase B: merge col-split partials + Jacobi update ---
__global__ void merge_kernel(const float* __restrict__ p,
                             const float2* __restrict__ vp,
                             const float* __restrict__ xin,
                             float* __restrict__ xout, int nv, int nprows) {
    int i = blockIdx.x * BLK + threadIdx.x;
    if (i >= nv) return;
    float c = 0.0f;
    #pragma unroll
    for (int cs = 0; cs < NCS; ++cs) c += p[(size_t)cs * nprows + i];
    float2 q = vp[i];
    xout[i] = xin[i] + q.x - q.y * c;
}

extern "C" void kernel_launch(void* const* d_in, const int* in_sizes, int n_in,
                              void* d_out, int out_size, void* d_ws, size_t ws_size,
                              hipStream_t stream) {
    const float* vattr = (const float*)d_in[1];
    const void*  eij   = (const void*)d_in[2];
    const float* eattr = (const float*)d_in[3];
    const float* g     = (const float*)d_in[4];
    const int nv = in_sizes[1] / 3;   // 1,000,000
    const int ne = in_sizes[3] / 2;   // 16,000,000
    const int n_iters = 10;
    const int nrb  = (nv + RMSK) >> RSH;      // 62 rowbuckets of 16384 rows
    const int nseg = nrb * NCH;               // 7936 fine segments
    const int nh   = nseg * B1;               // ~2.03M
    const int nprows = nrb << RSH;            // 1,015,808

    // workspace layout
    char* ws = (char*)d_ws;
    size_t off = 0;
    auto alloc = [&](size_t bytes) -> void* {
        void* p = ws + off;
        off = (off + bytes + 255) & ~(size_t)255;
        return p;
    };
    ull* edges = (ull*)alloc((size_t)ne * 8);                  // 128MB packed
    uint* rc32 = (uint*)alloc((size_t)ne * 4);                 // 64MB sorted SoA
    unsigned short* af16 = (unsigned short*)alloc((size_t)ne * 2);  // 32MB
    uint* hist = (uint*)alloc((size_t)nh * 4);                 // ~8MB
    uint* part = (uint*)alloc(((size_t)(nh + BLK - 1) / BLK) * 4);
    float* p = (float*)alloc((size_t)NCS * nprows * 4);        // ~32.5MB
    float2* vp = (float2*)alloc((size_t)nv * 8);
    float*  xa = (float*) alloc((size_t)nv * 4);
    float*  xb = (float*) alloc((size_t)nv * 4);
    int*  flag = (int*)   alloc(256);

    const int vblocks = (nv + BLK - 1) / BLK;
    const int sblocks = (nh + BLK - 1) / BLK;   // 7936

    detect_kernel<<<1, 64, 0, stream>>>((const ull*)eij, flag);
    hist1_kernel<<<B1, BLKW, 0, stream>>>(eij, flag, hist, ne, nseg);
    scan1_kernel<<<sblocks, BLK, 0, stream>>>(hist, part, nh);
    scan2_kernel<<<1, BLK, 0, stream>>>(part, sblocks);
    scan3_kernel<<<sblocks, BLK, 0, stream>>>(hist, part, nh);
    scatter1_kernel<<<B1, BLKW, 0, stream>>>(eij, (const float2*)eattr, flag,
                                             hist, edges, ne, nseg);
    finesort_kernel<<<nseg, BLK, 0, stream>>>(edges, hist, rc32, af16, ne, nseg);
    vprep_kernel<<<vblocks, BLK, 0, stream>>>(vattr, g, vp, xa, nv);

    float* xin  = xa;
    float* xout = xb;
    for (int it = 0; it < n_iters; ++it) {
        iter_kernel<<<nrb * NCS, BLKW, 0, stream>>>(hist, rc32, af16, xin, p,
                                                    ne, nseg, nprows);
        float* dst = (it == n_iters - 1) ? (float*)d_out : xout;
        merge_kernel<<<vblocks, BLK, 0, stream>>>(p, vp, xin, dst, nv, nprows);
        float* t = xin; xin = dst; xout = t;
    }
}